// Round 5
// baseline (110.255 us; speedup 1.0000x reference)
//
#include <hip/hip_runtime.h>

// Problem constants (from reference setup_inputs)
constexpr int B = 4;
constexpr int L = 512;
constexpr int C = 128;
constexpr int LL = L * L;                 // 262144
constexpr int PAIRS = L * (L + 1) / 2;    // 131328 upper-tri pairs per batch
constexpr int POS_PER_HALF = 4;           // positions per 32-lane half-wave
constexpr int POS_PER_BLOCK = 32;         // 8 half-waves * 4

// ---------------------------------------------------------------------------
// Pass 1: y[b,l,m,:] = relu(feat[b,l,m,:]) . W   (no bias, no 0.5)
// written into d_out (y has the same shape as out). Gated: computed only
// where flag[l,m]|flag[m,l] != 0 (pass 2 never reads y elsewhere).
// All feature reads are row-sequential -> pure streaming.
// ---------------------------------------------------------------------------
__global__ __launch_bounds__(256) void proj_kernel(
    const float* __restrict__ feat,   // [B,L,L,C]
    const int*   __restrict__ flag,   // [B,L,L]
    const float* __restrict__ W,      // [C,2]
    float*       __restrict__ y)      // [B,L,L,2]  (== d_out)
{
    const int tid = threadIdx.x;
    const int sl  = tid & 31;         // sub-lane within half
    const int hw  = tid >> 5;         // half-wave 0..7
    const int p0  = blockIdx.x * POS_PER_BLOCK + hw * POS_PER_HALF;

    const int b   = p0 >> 18;         // / LL
    const int rem = p0 & (LL - 1);
    const int l   = rem >> 9;         // / L
    const int m0  = rem & (L - 1);    // block's 32 positions stay in one row

    // per-lane W fragment: channels 4sl..4sl+3, O=2 each
    const float4 w0 = *(const float4*)(W + sl * 8);
    const float4 w1 = *(const float4*)(W + sl * 8 + 4);

    // Phase A: flags (straight contiguous, mirror strided; half-uniform)
    int fS[POS_PER_HALF], fM[POS_PER_HALF];
    #pragma unroll
    for (int k = 0; k < POS_PER_HALF; ++k) {
        const int m = m0 + k;
        fS[k] = flag[(size_t)b * LL + (size_t)l * L + m];
        fM[k] = flag[(size_t)b * LL + (size_t)m * L + l];
    }

    // Phase B: gated feature loads, all issued before any consumption
    float4 u[POS_PER_HALF];
    #pragma unroll
    for (int k = 0; k < POS_PER_HALF; ++k) {
        float4 uu = make_float4(0.f, 0.f, 0.f, 0.f);
        if ((fS[k] | fM[k]) != 0)
            uu = *(const float4*)(feat + ((size_t)p0 + k) * C + sl * 4);
        u[k] = uu;
    }

    // Phase C: relu + project + half-wave reduce + gated write
    #pragma unroll
    for (int k = 0; k < POS_PER_HALF; ++k) {
        const float x0 = fmaxf(u[k].x, 0.f);
        const float x1 = fmaxf(u[k].y, 0.f);
        const float x2 = fmaxf(u[k].z, 0.f);
        const float x3 = fmaxf(u[k].w, 0.f);
        const float s0 = x0 * w0.x + x1 * w0.z + x2 * w1.x + x3 * w1.z;
        const float s1 = x0 * w0.y + x1 * w0.w + x2 * w1.y + x3 * w1.w;

        // convergent parity-trick reduce over the 32-lane half (7 shfls)
        const float t0 = s0 + __shfl_xor(s0, 1, 64);
        const float t1 = s1 + __shfl_xor(s1, 1, 64);
        float v = (sl & 1) ? t1 : t0;
        v += __shfl_xor(v, 2, 64);
        v += __shfl_xor(v, 4, 64);
        v += __shfl_xor(v, 8, 64);
        v += __shfl_xor(v, 16, 64);
        const float other = __shfl_xor(v, 1, 64);

        if (sl == 0 && (fS[k] | fM[k]) != 0)
            *(float2*)(y + ((size_t)p0 + k) * 2) = make_float2(v, other);
    }
}

// ---------------------------------------------------------------------------
// Pass 2: out[l,m] = flag[l,m] ? 0.5*(y[l,m]+y[m,l]) + b : 0   (in place)
// One thread per symmetric pair (l<=m): reads both cells, writes both cells.
// Exclusive ownership of the pair -> race-free despite in-place update.
// y is 8.4 MB -> mirror reads served by L2/L3.
// ---------------------------------------------------------------------------
__device__ __forceinline__ int tri_offset(int l) {
    return l * L - (l * (l - 1)) / 2;
}

__global__ __launch_bounds__(256) void sym_kernel(
    const int*   __restrict__ flag,   // [B,L,L]
    const float* __restrict__ bias,   // [2]
    float*                     out)   // [B,L,L,2] (y on input, out on output)
{
    const long long g = (long long)blockIdx.x * 256 + threadIdx.x;
    if (g >= (long long)B * PAIRS) return;
    const int b = (int)(g / PAIRS);
    const int p = (int)(g % PAIRS);

    // decode (l,m), l<=m from triangular index p
    float disc = (float)((2 * L + 1) * (2 * L + 1)) - 8.0f * (float)p;
    int l = (int)(((float)(2 * L + 1) - sqrtf(disc)) * 0.5f);
    l = min(max(l, 0), L - 1);
    while (l + 1 <= L - 1 && tri_offset(l + 1) <= p) ++l;
    while (tri_offset(l) > p) --l;
    const int m = l + (p - tri_offset(l));

    const size_t iS = (size_t)b * LL + (size_t)l * L + m;
    const size_t iM = (size_t)b * LL + (size_t)m * L + l;
    const int fS = flag[iS];
    const int fM = flag[iM];

    float2 val = make_float2(0.f, 0.f);
    if ((fS | fM) != 0) {
        const float2 a = *(const float2*)(out + iS * 2);
        const float2 c = *(const float2*)(out + iM * 2);
        val = make_float2(0.5f * (a.x + c.x) + bias[0],
                          0.5f * (a.y + c.y) + bias[1]);
    }
    const float2 zero = make_float2(0.f, 0.f);
    *(float2*)(out + iS * 2) = fS ? val : zero;
    if (m != l)
        *(float2*)(out + iM * 2) = fM ? val : zero;
}

extern "C" void kernel_launch(void* const* d_in, const int* in_sizes, int n_in,
                              void* d_out, int out_size, void* d_ws, size_t ws_size,
                              hipStream_t stream) {
    const float* feat = (const float*)d_in[0];
    const int*   flag = (const int*)d_in[1];
    const float* W    = (const float*)d_in[2];
    const float* bias = (const float*)d_in[3];
    float* out = (float*)d_out;

    const int blocks1 = (B * LL) / POS_PER_BLOCK;                 // 32768
    proj_kernel<<<blocks1, 256, 0, stream>>>(feat, flag, W, out);

    const long long pairsTotal = (long long)B * PAIRS;            // 525312
    const int blocks2 = (int)((pairsTotal + 255) / 256);          // 2052
    sym_kernel<<<blocks2, 256, 0, stream>>>(flag, bias, out);
}

// Round 6
// 103.917 us; speedup vs baseline: 1.0610x; 1.0610x over previous
//
#include <hip/hip_runtime.h>

// Problem constants (from reference setup_inputs)
constexpr int B = 4;
constexpr int L = 512;
constexpr int C = 128;
constexpr int LL = L * L;                 // 262144
constexpr int NT = L / 16;                // 32 tiles per dimension (16x16 tiles)
constexpr int TP = NT * (NT + 1) / 2;     // 528 unordered tile-pairs per batch
constexpr size_t GATE_BYTES = (size_t)B * LL;   // 1 MB uint8 gate map in ws

__device__ __forceinline__ int tri_off(int r) { return r * NT - (r * (r - 1)) / 2; }

__device__ __forceinline__ void decode_tile(int t, int& ta, int& tb) {
    const float disc = (float)((2 * NT + 1) * (2 * NT + 1)) - 8.0f * (float)t;
    int a = (int)(((float)(2 * NT + 1) - sqrtf(disc)) * 0.5f);
    a = min(max(a, 0), NT - 1);
    while (a + 1 <= NT - 1 && tri_off(a + 1) <= t) ++a;
    while (tri_off(a) > t) --a;
    ta = a; tb = a + (t - tri_off(a));
}

// ---------------------------------------------------------------------------
// Pass 0: gate[b,l,m] = (flag[l,m] | flag[m,l]) != 0, as uint8.
// 16x16 tile-pairs; both flag tiles read row-coalesced; transpose via LDS.
// ---------------------------------------------------------------------------
__global__ __launch_bounds__(256) void gate_kernel(
    const int* __restrict__ flag, unsigned char* __restrict__ gate)
{
    __shared__ int sU[16][17], sV[16][17];
    const int bid = blockIdx.x;
    const int b = bid / TP;
    int ta, tb; decode_tile(bid - b * TP, ta, tb);

    const int i = threadIdx.x >> 4, j = threadIdx.x & 15;
    const size_t base = (size_t)b * LL;
    const int rA = ta * 16 + i, rB = tb * 16 + i;
    const int cA = ta * 16 + j, cB = tb * 16 + j;

    const int U = flag[base + (size_t)rA * L + cB];   // tile (ta,tb)
    const int V = flag[base + (size_t)rB * L + cA];   // tile (tb,ta)
    sU[i][j] = U; sV[i][j] = V;
    __syncthreads();

    // gate[rA,cB] = f[rA,cB] | f[cB,rA];  f[cB,rA] = V-tile(row j, col i)
    gate[base + (size_t)rA * L + cB] = (unsigned char)((U | sV[j][i]) ? 1 : 0);
    if (ta != tb)
        gate[base + (size_t)rB * L + cA] = (unsigned char)((V | sU[j][i]) ? 1 : 0);
}

// ---------------------------------------------------------------------------
// Pass 1: y[p] = relu(feat[p,:]) . W for gate[p]!=0; pure sequential stream.
// Half-wave (32 lanes) per 4 positions; lane owns channels 4sl..4sl+3.
// ---------------------------------------------------------------------------
__global__ __launch_bounds__(256) void proj_kernel(
    const float*         __restrict__ feat,   // [B,L,L,C]
    const unsigned char* __restrict__ gate,   // [B*L*L]
    const float*         __restrict__ W,      // [C,2]
    float2*              __restrict__ y)      // [B*L*L] in ws
{
    const int tid = threadIdx.x;
    const int sl  = tid & 31;
    const int hw  = tid >> 5;
    const int p0  = blockIdx.x * 32 + hw * 4;

    const float4 w0 = *(const float4*)(W + sl * 8);
    const float4 w1 = *(const float4*)(W + sl * 8 + 4);

    const uchar4 g = *(const uchar4*)(gate + p0);
    const unsigned char ga[4] = {g.x, g.y, g.z, g.w};

    float4 u[4];
    #pragma unroll
    for (int k = 0; k < 4; ++k) {
        float4 uu = make_float4(0.f, 0.f, 0.f, 0.f);
        if (ga[k])
            uu = *(const float4*)(feat + ((size_t)p0 + k) * C + sl * 4);
        u[k] = uu;
    }

    #pragma unroll
    for (int k = 0; k < 4; ++k) {
        const float x0 = fmaxf(u[k].x, 0.f);
        const float x1 = fmaxf(u[k].y, 0.f);
        const float x2 = fmaxf(u[k].z, 0.f);
        const float x3 = fmaxf(u[k].w, 0.f);
        const float s0 = x0 * w0.x + x1 * w0.z + x2 * w1.x + x3 * w1.z;
        const float s1 = x0 * w0.y + x1 * w0.w + x2 * w1.y + x3 * w1.w;

        // convergent parity-trick reduce over the 32-lane half (7 shfls)
        const float t0 = s0 + __shfl_xor(s0, 1, 64);
        const float t1 = s1 + __shfl_xor(s1, 1, 64);
        float v = (sl & 1) ? t1 : t0;
        v += __shfl_xor(v, 2, 64);
        v += __shfl_xor(v, 4, 64);
        v += __shfl_xor(v, 8, 64);
        v += __shfl_xor(v, 16, 64);
        const float other = __shfl_xor(v, 1, 64);

        if (sl == 0 && ga[k])
            y[p0 + k] = make_float2(v, other);
    }
}

// ---------------------------------------------------------------------------
// Pass 2: out[l,m] = flag[l,m] ? 0.5*(y[l,m]+y[m,l]) + bias : 0.
// 16x16 tile-pairs; every global access row-coalesced; transpose via LDS.
// Each output cell written by exactly one block.
// ---------------------------------------------------------------------------
__global__ __launch_bounds__(256) void sym_kernel(
    const int*    __restrict__ flag,
    const float*  __restrict__ bias,
    const float2* __restrict__ y,
    float2*       __restrict__ out)
{
    __shared__ float2 sA[16][17], sB[16][17];
    const int bid = blockIdx.x;
    const int b = bid / TP;
    int ta, tb; decode_tile(bid - b * TP, ta, tb);

    const int i = threadIdx.x >> 4, j = threadIdx.x & 15;
    const size_t base = (size_t)b * LL;
    const int rA = ta * 16 + i, rB = tb * 16 + i;
    const int cA = ta * 16 + j, cB = tb * 16 + j;

    const size_t iA = base + (size_t)rA * L + cB;   // tile (ta,tb) cell
    const size_t iB = base + (size_t)rB * L + cA;   // tile (tb,ta) cell

    const float2 yA = y[iA];
    const float2 yB = y[iB];
    const int    fA = flag[iA];
    const int    fB = flag[iB];
    sA[i][j] = yA; sB[i][j] = yB;
    __syncthreads();

    const float b0 = bias[0], b1 = bias[1];
    const float2 zero = make_float2(0.f, 0.f);

    // mirror of cell (rA,cB) is (cB,rA) = B-tile (row j, col i)
    const float2 mA = sB[j][i];
    const float2 vA = make_float2(0.5f * (yA.x + mA.x) + b0,
                                  0.5f * (yA.y + mA.y) + b1);
    out[iA] = fA ? vA : zero;

    if (ta != tb) {
        const float2 mB = sA[j][i];
        const float2 vB = make_float2(0.5f * (yB.x + mB.x) + b0,
                                      0.5f * (yB.y + mB.y) + b1);
        out[iB] = fB ? vB : zero;
    }
}

extern "C" void kernel_launch(void* const* d_in, const int* in_sizes, int n_in,
                              void* d_out, int out_size, void* d_ws, size_t ws_size,
                              hipStream_t stream) {
    const float* feat = (const float*)d_in[0];
    const int*   flag = (const int*)d_in[1];
    const float* W    = (const float*)d_in[2];
    const float* bias = (const float*)d_in[3];
    float2* out = (float2*)d_out;

    unsigned char* gate = (unsigned char*)d_ws;
    float2*        y    = (float2*)((char*)d_ws + GATE_BYTES);  // needs ~9 MB ws

    const int tileBlocks = B * TP;                 // 2112
    gate_kernel<<<tileBlocks, 256, 0, stream>>>(flag, gate);

    const int projBlocks = (B * LL) / 32;          // 32768
    proj_kernel<<<projBlocks, 256, 0, stream>>>(feat, gate, W, y);

    sym_kernel<<<tileBlocks, 256, 0, stream>>>(flag, bias, y, out);
}

// Round 7
// 98.677 us; speedup vs baseline: 1.1173x; 1.0531x over previous
//
#include <hip/hip_runtime.h>

// Problem constants (from reference setup_inputs)
constexpr int B = 4;
constexpr int L = 512;
constexpr int C = 128;
constexpr int LL = L * L;
constexpr int NT = L / 8;                   // 64 tiles per dimension
constexpr int NTILES = NT * (NT + 1) / 2;   // 2080 upper-tri tiles per batch

__device__ __forceinline__ int tri_off(int r) { return r * NT - (r * (r - 1)) / 2; }

// Block = 256 threads = 4 waves; 8x8 pair tile (l<=m). Wave w handles cols
// j=2w (group 0) and j=2w+1 (group 1), rows i=0..7 each.
// Wave = one pair per step: lanes 0-31 load feat[l,m,:] (float4/lane),
// lanes 32-63 load feat[m,l,:]. The gate (flag[l,m]|flag[m,l]) is
// WAVE-UNIFORM and forced through readfirstlane -> scalar s_cbranch, so
// gated-off pairs issue NO feature load instructions at all (this is the
// experiment: does real load-skipping cut DRAM time vs rounds 4-6?).
__global__ __launch_bounds__(256) void cmg_kernel(
    const float* __restrict__ feat,   // [B,L,L,C]
    const int*   __restrict__ flag,   // [B,L,L]
    const float* __restrict__ W,      // [C,2]
    const float* __restrict__ bias,   // [2]
    float*       __restrict__ out)    // [B,L,L,2]
{
    const int tid  = threadIdx.x;
    const int lane = tid & 63;
    const int w    = tid >> 6;       // wave 0..3
    const int h    = lane >> 5;      // 0: (l,m) row, 1: (m,l) row
    const int sl   = lane & 31;      // sub-lane: channels 4sl..4sl+3

    // ---- decode batch + triangular tile (tl, tm), tl <= tm ----
    const int bid = blockIdx.x;
    const int b   = bid / NTILES;
    const int t   = bid - b * NTILES;
    const float disc = (float)((2 * NT + 1) * (2 * NT + 1)) - 8.0f * (float)t;
    int tl = (int)(((float)(2 * NT + 1) - sqrtf(disc)) * 0.5f);
    tl = min(max(tl, 0), NT - 1);
    while (tl + 1 <= NT - 1 && tri_off(tl + 1) <= t) ++tl;
    while (tri_off(tl) > t) --tl;
    const int tm = tl + (t - tri_off(tl));
    const int l0 = tl * 8, m0 = tm * 8;
    const bool diag = (tl == tm);

    // per-lane W fragment: channels 4sl..4sl+3, O=2 each
    const float4 w0 = *(const float4*)(W + sl * 8);
    const float4 w1 = *(const float4*)(W + sl * 8 + 4);
    const float b0 = bias[0], b1 = bias[1];

    const size_t bb = (size_t)b * LL;

    #pragma unroll
    for (int g = 0; g < 2; ++g) {
        const int j = 2 * w + g;
        const int m = m0 + j;

        // ---- Phase A: flags (wave-uniform addresses -> broadcast loads) ----
        int fS[8], fM[8];
        #pragma unroll
        for (int i = 0; i < 8; ++i) {
            const int l = l0 + i;
            fS[i] = flag[bb + (size_t)l * L + m];
            fM[i] = flag[bb + (size_t)m * L + l];
        }

        // ---- Phase B: scalar-gated staged loads (no instruction if gated) ----
        float4 u[8];
        #pragma unroll
        for (int i = 0; i < 8; ++i) {
            const int l = l0 + i;
            float4 uu = make_float4(0.f, 0.f, 0.f, 0.f);
            const int gate = __builtin_amdgcn_readfirstlane(fS[i] | fM[i]);
            const bool valid = !diag || (i <= j);   // uniform
            if (valid && gate != 0) {
                const float* rowA = feat + (bb + (size_t)l * L + m) * C;
                const float* rowB = feat + (bb + (size_t)m * L + l) * C;
                const float* src  = (h == 0) ? (rowA + sl * 4) : (rowB + sl * 4);
                uu = *(const float4*)src;
            }
            u[i] = uu;
        }

        // ---- Phase C: project + 64-lane reduce + write ----
        #pragma unroll
        for (int i = 0; i < 8; ++i) {
            const int l = l0 + i;
            const float x0 = fmaxf(u[i].x, 0.f);
            const float x1 = fmaxf(u[i].y, 0.f);
            const float x2 = fmaxf(u[i].z, 0.f);
            const float x3 = fmaxf(u[i].w, 0.f);
            const float s0 = x0 * w0.x + x1 * w0.z + x2 * w1.x + x3 * w1.z;
            const float s1 = x0 * w0.y + x1 * w0.w + x2 * w1.y + x3 * w1.w;

            // convergent parity-trick reduce over all 64 lanes (8 shfls)
            const float t0 = s0 + __shfl_xor(s0, 1, 64);
            const float t1 = s1 + __shfl_xor(s1, 1, 64);
            float v = (lane & 1) ? t1 : t0;   // even lanes: s0-class, odd: s1-class
            v += __shfl_xor(v, 2, 64);
            v += __shfl_xor(v, 4, 64);
            v += __shfl_xor(v, 8, 64);
            v += __shfl_xor(v, 16, 64);
            v += __shfl_xor(v, 32, 64);
            const float other = __shfl_xor(v, 1, 64);

            const bool valid = !diag || (i <= j);
            if (valid && lane == 0) {
                // v = reluLM.Wcol + reluML.Wcol summed over all 128 channels
                const size_t iS = bb + (size_t)l * L + m;
                const size_t iM = bb + (size_t)m * L + l;
                const float2 val  = make_float2(0.5f * v + b0, 0.5f * other + b1);
                const float2 zero = make_float2(0.f, 0.f);
                *(float2*)(out + iS * 2) = fS[i] ? val : zero;
                if (m != l)
                    *(float2*)(out + iM * 2) = fM[i] ? val : zero;
            }
        }
    }
}

extern "C" void kernel_launch(void* const* d_in, const int* in_sizes, int n_in,
                              void* d_out, int out_size, void* d_ws, size_t ws_size,
                              hipStream_t stream) {
    const float* feat = (const float*)d_in[0];
    const int*   flag = (const int*)d_in[1];
    const float* W    = (const float*)d_in[2];
    const float* bias = (const float*)d_in[3];
    float* out = (float*)d_out;

    const int blocks = B * NTILES;   // 8320
    cmg_kernel<<<blocks, 256, 0, stream>>>(feat, flag, W, bias, out);
}

// Round 8
// 87.871 us; speedup vs baseline: 1.2547x; 1.1230x over previous
//
#include <hip/hip_runtime.h>

// Problem constants (from reference setup_inputs)
constexpr int B = 4;
constexpr int L = 512;
constexpr int C = 128;
constexpr int NT = L / 8;                   // 64 tiles per dimension
constexpr int NTILES = NT * (NT + 1) / 2;   // 2080 upper-tri tiles per batch

__device__ __forceinline__ int tri_off(int r) {
    return r * NT - (r * (r - 1)) / 2;
}

// Round-4 structure (measured 87.5 us = 6.28 TB/s effective = m13 copy ceiling).
// Block = 256 threads = 4 waves; 8x8 pair tile per block (l<=m).
// Three-phase: (A) all flags, (B) all gated feature loads staged to regs,
// (C) 8 independent reduce chains + writes.
__global__ __launch_bounds__(256) void cmg_kernel(
    const float* __restrict__ feat,   // [B,L,L,C]
    const int*   __restrict__ flag,   // [B,L,L]
    const float* __restrict__ W,      // [C,2]
    const float* __restrict__ bias,   // [2]
    float*       __restrict__ out)    // [B,L,L,2]
{
    const int tid  = threadIdx.x;
    const int lane = tid & 63;
    const int w    = tid >> 6;       // wave 0..3
    const int h    = lane >> 5;      // half 0..1
    const int sl   = lane & 31;      // sub-lane 0..31

    // ---- decode batch + triangular tile (tl, tm), tl <= tm ----
    const int bid = blockIdx.x;
    const int b   = bid / NTILES;
    const int t   = bid - b * NTILES;
    const float disc = (float)((2 * NT + 1) * (2 * NT + 1)) - 8.0f * (float)t;
    int tl = (int)(((float)(2 * NT + 1) - sqrtf(disc)) * 0.5f);
    tl = min(max(tl, 0), NT - 1);
    while (tl + 1 <= NT - 1 && tri_off(tl + 1) <= t) ++tl;
    while (tri_off(tl) > t) --tl;
    const int tm = tl + (t - tri_off(tl));
    const int l0 = tl * 8, m0 = tm * 8;
    const bool diag = (tl == tm);

    const int j = 2 * w + h;         // tile col for this half (fixed)
    const int m = m0 + j;

    // per-lane W fragment: channels 4sl..4sl+3, O=2 each
    const float4 w0 = *(const float4*)(W + sl * 8);
    const float4 w1 = *(const float4*)(W + sl * 8 + 4);
    const float b0 = bias[0], b1 = bias[1];

    // ---- Phase A: flag loads ----
    int fLM[8], fML[8];
    #pragma unroll
    for (int it = 0; it < 8; ++it) {
        const int l = l0 + it;
        fLM[it] = flag[((size_t)b * L + l) * L + m];
        fML[it] = flag[((size_t)b * L + m) * L + l];
    }

    // ---- Phase B: gated feature loads, staged in registers ----
    float4 u[8], v4[8];
    #pragma unroll
    for (int it = 0; it < 8; ++it) {
        const int l = l0 + it;
        const bool active = !diag || (it <= j);
        const bool doLoad = active && ((fLM[it] | fML[it]) != 0);
        float4 uu = make_float4(0.f, 0.f, 0.f, 0.f);
        float4 vv = uu;
        if (doLoad) {
            const float* baseU = feat + (((size_t)b * L + l) * L + (m0 + 2 * w)) * C;
            uu = *(const float4*)(baseU + lane * 4);          // upper row, full wave
            const float* baseL = feat + (((size_t)b * L + m) * L + l) * C;
            vv = *(const float4*)(baseL + sl * 4);            // lower row, per half
        }
        u[it] = uu;
        v4[it] = vv;
    }

    // ---- Phase C: reduce + write ----
    #pragma unroll
    for (int it = 0; it < 8; ++it) {
        const int l = l0 + it;
        const bool active = !diag || (it <= j);

        const float x0 = 0.5f * (fmaxf(u[it].x, 0.f) + fmaxf(v4[it].x, 0.f));
        const float x1 = 0.5f * (fmaxf(u[it].y, 0.f) + fmaxf(v4[it].y, 0.f));
        const float x2 = 0.5f * (fmaxf(u[it].z, 0.f) + fmaxf(v4[it].z, 0.f));
        const float x3 = 0.5f * (fmaxf(u[it].w, 0.f) + fmaxf(v4[it].w, 0.f));

        const float s0 = x0 * w0.x + x1 * w0.z + x2 * w1.x + x3 * w1.z;
        const float s1 = x0 * w0.y + x1 * w0.w + x2 * w1.y + x3 * w1.w;

        // convergent parity-trick reduce over the 32-lane half (7 shfls)
        const float t0 = s0 + __shfl_xor(s0, 1, 64);
        const float t1 = s1 + __shfl_xor(s1, 1, 64);
        float v = (sl & 1) ? t1 : t0;
        v += __shfl_xor(v, 2, 64);
        v += __shfl_xor(v, 4, 64);
        v += __shfl_xor(v, 8, 64);
        v += __shfl_xor(v, 16, 64);
        const float other = __shfl_xor(v, 1, 64);

        if (active && sl == 0) {
            const size_t idxLM = ((size_t)b * L + l) * L + m;
            const size_t idxML = ((size_t)b * L + m) * L + l;
            const float2 val  = make_float2(v + b0, other + b1);
            const float2 zero = make_float2(0.f, 0.f);
            *(float2*)(out + idxLM * 2) = fLM[it] ? val : zero;
            if (m != l)
                *(float2*)(out + idxML * 2) = fML[it] ? val : zero;
        }
    }
}

extern "C" void kernel_launch(void* const* d_in, const int* in_sizes, int n_in,
                              void* d_out, int out_size, void* d_ws, size_t ws_size,
                              hipStream_t stream) {
    const float* feat = (const float*)d_in[0];
    const int*   flag = (const int*)d_in[1];
    const float* W    = (const float*)d_in[2];
    const float* bias = (const float*)d_in[3];
    float* out = (float*)d_out;

    const int blocks = B * NTILES;   // 8320
    cmg_kernel<<<blocks, 256, 0, stream>>>(feat, flag, W, bias, out);
}